// Round 1
// baseline (271.960 us; speedup 1.0000x reference)
//
#include <hip/hip_runtime.h>

// out[n,m,:] = normalize(emb[m, g, :]),  g = gene_seq[n,m]
// N=256, M=2000, D=128. Output 262 MB fp32 -> write-BW bound (~41 us floor
// at the 6.4 TB/s the harness fill kernels demonstrate).
//
// R4 theory: old phase-2 mapping (j stride 6400) made every block touch the
// whole 4 MB table -> per-XCD working set == per-XCD L2 size (4 MB) while the
// write stream flows through the same L2 -> table thrashes to L3/HBM.
// Fix: (1) phase 1 now materializes the fully NORMALIZED table (4 MB in ws),
// removing the inv_norm load + mul from the hot loop; (2) phase 2 uses
// m-contiguous 64-gene tiles with XCD-stable assignment (blockIdx%8 -> XCD,
// empirical round-robin): XCD k owns genes [256k, 256k+256) -> 512 KB table
// slice + 256 KB gene_seq columns, L2-resident. NT stores keep the write
// stream from allocating in L2.

#define N_SEQ     256
#define M_GENES   2000
#define D_DIM     128
#define ROWS      (M_GENES * 4)            // 8000 table rows
#define P1_BLOCKS (ROWS * 32 / 256)        // 1000 blocks, 32 lanes/row
#define TILE_M    64                       // genes per phase-2 block
#define N_TILES   32                       // 32*64 = 2048 >= 2000 (tile 31 ragged)
#define P2_IT     8                        // 256 thr * 8 it = 2048 = TILE_M*32 units
#define P2_BLOCKS (N_TILES * N_SEQ)        // 8192 blocks

typedef float vfloat4 __attribute__((ext_vector_type(4)));

// Phase 1: normalized table into ws: tableN[row][d] = emb[row][d] / max(||row||, eps)
__global__ __launch_bounds__(256) void norm_table_kernel(
    const float* __restrict__ emb,         // (M,4,D) = (8000,128)
    float*       __restrict__ tableN)      // (8000,128) normalized, in d_ws
{
    const int idx = blockIdx.x * 256 + threadIdx.x;   // 0 .. 255999
    const int off = idx << 2;                         // == row*128 + c*4 exactly

    const vfloat4 v = *reinterpret_cast<const vfloat4*>(emb + off);
    float ss = v.x * v.x + v.y * v.y + v.z * v.z + v.w * v.w;
    ss += __shfl_xor(ss, 1, 32);
    ss += __shfl_xor(ss, 2, 32);
    ss += __shfl_xor(ss, 4, 32);
    ss += __shfl_xor(ss, 8, 32);
    ss += __shfl_xor(ss, 16, 32);
    const float inv = 1.0f / fmaxf(sqrtf(ss), 1e-12f);

    const vfloat4 o = v * inv;
    *reinterpret_cast<vfloat4*>(tableN + off) = o;    // regular store: WANT L2/L3 allocate
}

// Phase 2: pure gather-copy of normalized rows.
// blockIdx.x -> (xcd, tile, n) so that XCD k = id%8 always works on tiles
// [4k, 4k+4) = genes [256k, 256k+256): per-XCD table slice 512 KB, L2-resident.
__global__ __launch_bounds__(256) void gather_kernel(
    const int*   __restrict__ gene_seq,    // (N,M)
    const float* __restrict__ tableN,      // (8000,128) normalized
    float*       __restrict__ out)         // (N,M,D)
{
    const int id   = blockIdx.x;           // 0 .. 8191
    const int xcd  = id & 7;               // empirical XCD round-robin
    const int q    = id >> 3;              // 0 .. 1023
    const int tile = (xcd << 2) | (q >> 8);// 0 .. 31, stable per XCD
    const int n    = q & 255;

    const int* __restrict__ gs   = gene_seq + n * M_GENES;
    float*     __restrict__ outn = out + (size_t)n * (M_GENES * D_DIM);
    const int m0 = tile * TILE_M;

    if (m0 + TILE_M <= M_GENES) {
        // hot path: branch-free, 8 independent gather/store units per thread
        #pragma unroll
        for (int it = 0; it < P2_IT; ++it) {
            const int u   = it * 256 + threadIdx.x;       // 0 .. 2047, contiguous
            const int m   = m0 + (u >> 5);
            const int c4  = (u & 31) << 2;
            const int row = (m << 2) + gs[m];             // independent across it
            const vfloat4 v = *reinterpret_cast<const vfloat4*>(tableN + (row << 7) + c4);
            __builtin_nontemporal_store(v, reinterpret_cast<vfloat4*>(outn + (m << 7) + c4));
        }
    } else {
        // ragged tail: tile 31 covers m in [1984, 2048); only m < 2000 valid
        #pragma unroll
        for (int it = 0; it < P2_IT; ++it) {
            const int u = it * 256 + threadIdx.x;
            const int m = m0 + (u >> 5);
            if (m < M_GENES) {
                const int c4  = (u & 31) << 2;
                const int row = (m << 2) + gs[m];
                const vfloat4 v = *reinterpret_cast<const vfloat4*>(tableN + (row << 7) + c4);
                __builtin_nontemporal_store(v, reinterpret_cast<vfloat4*>(outn + (m << 7) + c4));
            }
        }
    }
}

extern "C" void kernel_launch(void* const* d_in, const int* in_sizes, int n_in,
                              void* d_out, int out_size, void* d_ws, size_t ws_size,
                              hipStream_t stream) {
    const int*   gene_seq = (const int*)d_in[0];
    const float* emb      = (const float*)d_in[1];
    float*       out      = (float*)d_out;
    float*       tableN   = (float*)d_ws;              // 8000*128 fp32 = 4 MB

    // Phase 1: normalize the whole table once (read 4 MB, write 4 MB)
    norm_table_kernel<<<dim3(P1_BLOCKS), dim3(256), 0, stream>>>(emb, tableN);

    // Phase 2: XCD-local gather of normalized rows, NT streaming stores
    gather_kernel<<<dim3(P2_BLOCKS), dim3(256), 0, stream>>>(gene_seq, tableN, out);
}

// Round 2
// 257.301 us; speedup vs baseline: 1.0570x; 1.0570x over previous
//
#include <hip/hip_runtime.h>

// out[n,m,:] = normalize(emb[m, g, :]),  g = gene_seq[n,m]
// N=256, M=2000, D=128. Output 262 MB fp32.
//
// R5 theory: the previous two-phase gather re-read the table per (n,m); its
// own 262 MB write stream flushes L2/L3 continuously, so NO cache-resident
// table slice survives (this is why R4's XCD-localized slices were a no-op:
// the write stream evicts 512 KB just as easily as 4 MB). Observed gather
// ~100 us vs 41 us write floor == the re-fetched read traffic.
// Fix: capture the reuse in REGISTERS, which the write stream cannot evict.
// Each 64-lane wave owns 2 genes (lanes 0-31 gene m_a, lanes 32-63 gene m_b),
// preloads all 4 candidate rows (4 x vfloat4/lane = 16 VGPR), normalizes them
// in-register once, then loops over a 64-n chunk: broadcast g via shfl,
// 2-level cndmask row select, coalesced 1 KB/wave store per n.
// HBM traffic: 262 MB write + ~16 MB emb (4x reuse-redundancy across n-chunks)
// + ~4 MB gene_seq. Single kernel, no workspace, regular stores (the harness
// fill proves plain stores reach 6.33 TB/s; nt is unproven and now unneeded).

#define N_SEQ   256
#define M_GENES 2000
#define D_DIM   128
#define GENES_PER_BLOCK 8                  // 4 waves x 2 genes
#define N_CHUNK 64                         // n's per block
#define GRID_X  (M_GENES / GENES_PER_BLOCK)  // 250
#define GRID_Y  (N_SEQ / N_CHUNK)            // 4  -> 1000 blocks

typedef float vfloat4 __attribute__((ext_vector_type(4)));

__global__ __launch_bounds__(256) void fused_gather_kernel(
    const int*   __restrict__ gene_seq,    // (N,M)
    const float* __restrict__ emb,         // (M,4,D)
    float*       __restrict__ out)         // (N,M,D)
{
    const int tid  = threadIdx.x;
    const int wave = tid >> 6;             // 0..3
    const int lane = tid & 63;
    const int c    = lane & 31;            // float4 index within a 512 B row

    const int m0    = blockIdx.x * GENES_PER_BLOCK;
    const int n0    = blockIdx.y * N_CHUNK;
    const int m_sel = m0 + (wave << 1) + (lane >> 5);   // my half's gene

    // ---- Preload + normalize the 4 candidate rows of my gene (registers) ----
    vfloat4 r[4];
    #pragma unroll
    for (int g = 0; g < 4; ++g) {
        const vfloat4 v = *reinterpret_cast<const vfloat4*>(
            emb + (((m_sel << 2) + g) << 7) + (c << 2));
        float ss = v.x * v.x + v.y * v.y + v.z * v.z + v.w * v.w;
        ss += __shfl_xor(ss, 1, 32);       // width 32: halves reduce independently
        ss += __shfl_xor(ss, 2, 32);
        ss += __shfl_xor(ss, 4, 32);
        ss += __shfl_xor(ss, 8, 32);
        ss += __shfl_xor(ss, 16, 32);
        const float inv = 1.0f / fmaxf(sqrtf(ss), 1e-12f);
        r[g] = v * inv;
    }

    // ---- Preload g for all 64 n's of this chunk (2 regs/lane) ----
    // lane (half,c) holds g(n0+c, m_sel) and g(n0+32+c, m_sel)
    const int g0 = gene_seq[(n0 + c)      * M_GENES + m_sel];
    const int g1 = gene_seq[(n0 + 32 + c) * M_GENES + m_sel];

    float* __restrict__ outbase = out + (size_t)(m_sel << 7) + (c << 2);

    // ---- Stream the n-loop: broadcast g, cndmask-select row, store ----
    #pragma unroll 4
    for (int n = 0; n < N_CHUNK; ++n) {
        const int src = (lane & 32) | (n & 31);         // same half, lane c = n&31
        const int gv  = __shfl((n < 32) ? g0 : g1, src, 64);

        const vfloat4 lo = (gv & 1) ? r[1] : r[0];
        const vfloat4 hi = (gv & 1) ? r[3] : r[2];
        const vfloat4 v  = (gv & 2) ? hi : lo;

        *reinterpret_cast<vfloat4*>(
            outbase + (size_t)(n0 + n) * (M_GENES * D_DIM)) = v;
    }
}

extern "C" void kernel_launch(void* const* d_in, const int* in_sizes, int n_in,
                              void* d_out, int out_size, void* d_ws, size_t ws_size,
                              hipStream_t stream) {
    const int*   gene_seq = (const int*)d_in[0];
    const float* emb      = (const float*)d_in[1];
    float*       out      = (float*)d_out;

    fused_gather_kernel<<<dim3(GRID_X, GRID_Y), dim3(256), 0, stream>>>(
        gene_seq, emb, out);
}